// Round 17
// baseline (75.147 us; speedup 1.0000x reference)
//
#include <hip/hip_runtime.h>
#include <math.h>

// ---------------- constants ----------------
#define Bsz   8
#define D     256      // d_model = num_heads = num_patches = 256
#define S     257      // seq len
#define MLP   1024
#define NCLS  1000
#define M_ROWS (Bsz * S)   // 2056

typedef unsigned int u32;
typedef unsigned short u16;
typedef __attribute__((ext_vector_type(8))) short bshort8;
typedef __attribute__((ext_vector_type(4))) float f32x4;

__device__ __forceinline__ float wave_sum(float v) {
  #pragma unroll
  for (int m = 1; m < 64; m <<= 1) v += __shfl_xor(v, m, 64);
  return v;
}

__device__ __forceinline__ u16 f2bf(float f) {
  u32 u = __float_as_uint(f);
  u += 0x7FFFu + ((u >> 16) & 1u);   // RNE
  return (u16)(u >> 16);
}
__device__ __forceinline__ float bf2f(u16 h) { return __uint_as_float(((u32)h) << 16); }
__device__ __forceinline__ u32 pk2(u16 a, u16 b) { return (u32)a | ((u32)b << 16); }
__device__ __forceinline__ float fexp2(float x) { return __builtin_amdgcn_exp2f(x); }

// ---------------- patch embed body (MFMA mini-GEMM, cls fused) ----------------
__device__ __forceinline__ void patch_body(int blk, int tid,
                                           const float* __restrict__ x,
                                           const float* __restrict__ pw,
                                           const float* __restrict__ pb,
                                           const float* __restrict__ pos,
                                           const float* __restrict__ ct,
                                           float* __restrict__ t,
                                           char* smem) {
  u16* sAh = (u16*)smem;
  u16* sAl = (u16*)(smem + 8192);
  u16* sBh = (u16*)(smem + 16384);
  u16* sBl = (u16*)(smem + 24576);
  const int n = blk >> 2;
  const int col0 = (blk & 3) * 64;
  const int pi = n >> 4, pj = n & 15;
  const int lane = tid & 63;
  const int w = tid >> 6;
  const int fr = lane & 15, g = lane >> 4;
  const int sr = tid >> 2, sc = tid & 3;
  const int arow = sr > 7 ? 7 : sr;   // M=8, clamp
  const u32 off0 = (u32)(sr * 128) + ((u32)((2 * sc)     ^ (sr & 7)) << 4);
  const u32 off1 = (u32)(sr * 128) + ((u32)((2 * sc + 1) ^ (sr & 7)) << 4);
  const float* ap32 = x + (size_t)arow * 65536 + (size_t)(pi * 16) * 256 + pj * 16;
  const float* bp32 = pw + (size_t)(col0 + sr) * 65536 + (size_t)n * 256 + sc * 16;

  if ((blk & 3) == 0 && tid < 8)
    t[((size_t)tid * S) * D + n] = ct[n] + pos[n];

  f32x4 acc = {0, 0, 0, 0}, ac2 = {0, 0, 0, 0};

  for (int k0 = 0; k0 < 256; k0 += 64) {
    const float* asrc = ap32 + (size_t)((k0 >> 4) + sc) * 256;
    float fa[16], fb[16];
    #pragma unroll
    for (int i = 0; i < 4; ++i) {
      float4 f4 = *(const float4*)(asrc + i * 4);
      fa[i*4+0] = f4.x; fa[i*4+1] = f4.y; fa[i*4+2] = f4.z; fa[i*4+3] = f4.w;
      float4 g4 = *(const float4*)(bp32 + k0 + i * 4);
      fb[i*4+0] = g4.x; fb[i*4+1] = g4.y; fb[i*4+2] = g4.z; fb[i*4+3] = g4.w;
    }
    u16 ah16[16], al16[16], bh16[16], bl16[16];
    #pragma unroll
    for (int i = 0; i < 16; ++i) {
      u16 h = f2bf(fa[i]); ah16[i] = h; al16[i] = f2bf(fa[i] - bf2f(h));
      u16 hb = f2bf(fb[i]); bh16[i] = hb; bl16[i] = f2bf(fb[i] - bf2f(hb));
    }
    __syncthreads();
    *(uint4*)((char*)sAh + off0) = make_uint4(pk2(ah16[0],ah16[1]), pk2(ah16[2],ah16[3]), pk2(ah16[4],ah16[5]), pk2(ah16[6],ah16[7]));
    *(uint4*)((char*)sAh + off1) = make_uint4(pk2(ah16[8],ah16[9]), pk2(ah16[10],ah16[11]), pk2(ah16[12],ah16[13]), pk2(ah16[14],ah16[15]));
    *(uint4*)((char*)sAl + off0) = make_uint4(pk2(al16[0],al16[1]), pk2(al16[2],al16[3]), pk2(al16[4],al16[5]), pk2(al16[6],al16[7]));
    *(uint4*)((char*)sAl + off1) = make_uint4(pk2(al16[8],al16[9]), pk2(al16[10],al16[11]), pk2(al16[12],al16[13]), pk2(al16[14],al16[15]));
    *(uint4*)((char*)sBh + off0) = make_uint4(pk2(bh16[0],bh16[1]), pk2(bh16[2],bh16[3]), pk2(bh16[4],bh16[5]), pk2(bh16[6],bh16[7]));
    *(uint4*)((char*)sBh + off1) = make_uint4(pk2(bh16[8],bh16[9]), pk2(bh16[10],bh16[11]), pk2(bh16[12],bh16[13]), pk2(bh16[14],bh16[15]));
    *(uint4*)((char*)sBl + off0) = make_uint4(pk2(bl16[0],bl16[1]), pk2(bl16[2],bl16[3]), pk2(bl16[4],bl16[5]), pk2(bl16[6],bl16[7]));
    *(uint4*)((char*)sBl + off1) = make_uint4(pk2(bl16[8],bl16[9]), pk2(bl16[10],bl16[11]), pk2(bl16[12],bl16[13]), pk2(bl16[14],bl16[15]));
    __syncthreads();
    #pragma unroll
    for (int ks = 0; ks < 2; ++ks) {
      int rA = fr;
      u32 oa = (u32)(rA * 128) + ((u32)((ks * 4 + g) ^ (rA & 7)) << 4);
      bshort8 ah = *(const bshort8*)((const char*)sAh + oa);
      bshort8 al = *(const bshort8*)((const char*)sAl + oa);
      int rB = w * 16 + fr;
      u32 ob = (u32)(rB * 128) + ((u32)((ks * 4 + g) ^ (rB & 7)) << 4);
      bshort8 bh = *(const bshort8*)((const char*)sBh + ob);
      bshort8 bl = *(const bshort8*)((const char*)sBl + ob);
      acc = __builtin_amdgcn_mfma_f32_16x16x32_bf16(ah, bh, acc, 0, 0, 0);
      ac2 = __builtin_amdgcn_mfma_f32_16x16x32_bf16(ah, bl, ac2, 0, 0, 0);
      ac2 = __builtin_amdgcn_mfma_f32_16x16x32_bf16(al, bh, ac2, 0, 0, 0);
    }
  }
  if (g < 2) {
    int h = col0 + w * 16 + fr;
    float addend = pb[h * 256 + n] + pos[(1 + h) * 256 + n];
    #pragma unroll
    for (int r = 0; r < 4; ++r) {
      int b = g * 4 + r;
      t[((size_t)b * S + 1 + h) * D + n] = acc[r] + ac2[r] + addend;
    }
  }
}

// K/V weight split-convert
__device__ __forceinline__ void conv_copy2_body(int blk, int tid,
                                                const float* __restrict__ wk,
                                                const float* __restrict__ wv,
                                                u16* __restrict__ W) {
  int wsel = blk >> 6, tile = blk & 63;
  const float* src = wsel == 0 ? wk : wv;
  u16* oh = W + wsel * 131072;
  u16* ol = oh + 65536;
  int r0 = (tile >> 3) * 32, c0 = (tile & 7) * 32;
  int tr = tid >> 3, tc = (tid & 7) * 4;
  const float4 f = *(const float4*)(src + (size_t)(r0 + tr) * 256 + c0 + tc);
  u16 h0 = f2bf(f.x), h1 = f2bf(f.y), h2 = f2bf(f.z), h3 = f2bf(f.w);
  u16 l0 = f2bf(f.x - bf2f(h0)), l1 = f2bf(f.y - bf2f(h1));
  u16 l2 = f2bf(f.z - bf2f(h2)), l3 = f2bf(f.w - bf2f(h3));
  size_t o = (size_t)(r0 + tr) * 256 + c0 + tc;
  *(uint2*)(oh + o) = make_uint2(pk2(h0, h1), pk2(h2, h3));
  *(uint2*)(ol + o) = make_uint2(pk2(l0, l1), pk2(l2, l3));
}

// prefetch weights into L2/L3 (keeps loads live via asm)
__device__ __forceinline__ void prefetch_body(int blk, int tid,
                                              const float* __restrict__ p, int nfloat) {
  int base = blk * 4096 + tid * 4;
  float acc = 0.f;
  #pragma unroll
  for (int i = 0; i < 4; ++i) {
    int idx = base + i * 1024;
    if (idx + 3 < nfloat) {
      float4 f = *(const float4*)(p + idx);
      acc += (f.x + f.y) + (f.z + f.w);
    }
  }
  asm volatile("" :: "v"(acc));
}

// stage0: patch (0..1023) + K/V weight conv (1024..1151) + tail-weight L3 prefetch
__global__ __launch_bounds__(256) void stage0(const float* __restrict__ x,
                                              const float* __restrict__ pw,
                                              const float* __restrict__ pb,
                                              const float* __restrict__ pos,
                                              const float* __restrict__ ct,
                                              const float* __restrict__ wk,
                                              const float* __restrict__ wv,
                                              const float* __restrict__ proj_w,
                                              const float* __restrict__ mlp_w1,
                                              const float* __restrict__ mlp_w2,
                                              const float* __restrict__ head_w,
                                              u16* __restrict__ Wkv,
                                              float* __restrict__ t) {
  __shared__ __align__(16) char smem[32768];
  int blk = blockIdx.x, tid = threadIdx.x;
  if (blk < 1024)      patch_body(blk, tid, x, pw, pb, pos, ct, t, smem);
  else if (blk < 1152) conv_copy2_body(blk - 1024, tid, wk, wv, Wkv);
  else {
    int p = blk - 1152;
    if (p < 16)       prefetch_body(p, tid, proj_w, 65536);
    else if (p < 80)  prefetch_body(p - 16, tid, mlp_w1, 262144);
    else if (p < 144) prefetch_body(p - 80, tid, mlp_w2, 262144);
    else              prefetch_body(p - 144, tid, head_w, 256000);
  }
}

// ---------------- K/V GEMM with inline LN on A (replaces ln_split + kv_kernel) ----------------
// A[row][k] = LN(t[row])[k], split to bf16 h/l in staging; B pre-split Wkv planes.
__global__ __launch_bounds__(256) void kv_ln_kernel(const float* __restrict__ T,
                                                    const float* __restrict__ lngam,
                                                    const float* __restrict__ lnbet,
                                                    const u16* __restrict__ Wkv,
                                                    float* __restrict__ kk,
                                                    float* __restrict__ v) {
  __shared__ __align__(16) u16 sAh[4096];
  __shared__ __align__(16) u16 sAl[4096];
  __shared__ __align__(16) u16 sBh[4096];
  __shared__ __align__(16) u16 sBl[4096];
  __shared__ float smu[64], sst[64];
  const int z = blockIdx.z;
  const u16* Bh = Wkv + z * 131072;
  const u16* Bl = Bh + 65536;
  float* Cf = z == 0 ? kk : v;
  const int M = M_ROWS, K = 256;
  const int row0 = blockIdx.y * 64, col0 = blockIdx.x * 64;
  const int tid = threadIdx.x;
  const int lane = tid & 63;
  const int w = tid >> 6, wm = w >> 1, wn = w & 1;
  const int fr = lane & 15, gq = lane >> 4;
  const int sr = tid >> 2, sc = tid & 3;
  int arow = row0 + sr; if (arow > M - 1) arow = M - 1;
  const u32 off0 = (u32)(sr * 128) + ((u32)((2 * sc)     ^ (sr & 7)) << 4);
  const u32 off1 = (u32)(sr * 128) + ((u32)((2 * sc + 1) ^ (sr & 7)) << 4);

  // phase 0: LN stats for the 64-row tile (per-row math identical to old ln_split)
  for (int r = w; r < 64; r += 4) {
    int row = row0 + r; if (row > M - 1) row = M - 1;
    const float* p = T + (size_t)row * 256;
    float4 vv = *(const float4*)&p[lane * 4];
    float s = wave_sum(vv.x + vv.y + vv.z + vv.w);
    float mu = s * (1.0f / 256.0f);
    float dx = vv.x - mu, dy = vv.y - mu, dz = vv.z - mu, dw = vv.w - mu;
    float qv = wave_sum(dx * dx + dy * dy + dz * dz + dw * dw);
    float rs = 1.0f / sqrtf(qv * (1.0f / 256.0f) + 1e-5f);
    if (lane == 0) { smu[r] = mu; sst[r] = rs; }
  }
  __syncthreads();
  const float mu = smu[sr];
  const float rs = sst[sr];
  const float* ap32 = T + (size_t)arow * K + sc * 16;
  const u16* bhp = Bh + (size_t)(col0 + sr) * K + sc * 16;
  const u16* blp = Bl + (size_t)(col0 + sr) * K + sc * 16;

  f32x4 acc[2][2], ac2[2][2];
  #pragma unroll
  for (int i = 0; i < 2; ++i)
    #pragma unroll
    for (int j = 0; j < 2; ++j) { acc[i][j] = (f32x4){0,0,0,0}; ac2[i][j] = (f32x4){0,0,0,0}; }

  for (int k0 = 0; k0 < K; k0 += 64) {
    float fv[16];
    #pragma unroll
    for (int i = 0; i < 4; ++i) {
      float4 f4 = *(const float4*)(ap32 + k0 + i * 4);
      float4 gg = *(const float4*)(lngam + k0 + sc * 16 + i * 4);
      float4 bb = *(const float4*)(lnbet + k0 + sc * 16 + i * 4);
      fv[i*4+0] = (f4.x - mu) * rs * gg.x + bb.x;
      fv[i*4+1] = (f4.y - mu) * rs * gg.y + bb.y;
      fv[i*4+2] = (f4.z - mu) * rs * gg.z + bb.z;
      fv[i*4+3] = (f4.w - mu) * rs * gg.w + bb.w;
    }
    u16 hh[16], ll[16];
    #pragma unroll
    for (int i = 0; i < 16; ++i) { u16 h = f2bf(fv[i]); hh[i] = h; ll[i] = f2bf(fv[i] - bf2f(h)); }
    uint4 wAh0 = make_uint4(pk2(hh[0],hh[1]), pk2(hh[2],hh[3]), pk2(hh[4],hh[5]), pk2(hh[6],hh[7]));
    uint4 wAh1 = make_uint4(pk2(hh[8],hh[9]), pk2(hh[10],hh[11]), pk2(hh[12],hh[13]), pk2(hh[14],hh[15]));
    uint4 wAl0 = make_uint4(pk2(ll[0],ll[1]), pk2(ll[2],ll[3]), pk2(ll[4],ll[5]), pk2(ll[6],ll[7]));
    uint4 wAl1 = make_uint4(pk2(ll[8],ll[9]), pk2(ll[10],ll[11]), pk2(ll[12],ll[13]), pk2(ll[14],ll[15]));
    uint4 wBh0 = *(const uint4*)(bhp + k0);
    uint4 wBh1 = *(const uint4*)(bhp + k0 + 8);
    uint4 wBl0 = *(const uint4*)(blp + k0);
    uint4 wBl1 = *(const uint4*)(blp + k0 + 8);
    __syncthreads();
    *(uint4*)((char*)sAh + off0) = wAh0;
    *(uint4*)((char*)sAh + off1) = wAh1;
    *(uint4*)((char*)sAl + off0) = wAl0;
    *(uint4*)((char*)sAl + off1) = wAl1;
    *(uint4*)((char*)sBh + off0) = wBh0;
    *(uint4*)((char*)sBh + off1) = wBh1;
    *(uint4*)((char*)sBl + off0) = wBl0;
    *(uint4*)((char*)sBl + off1) = wBl1;
    __syncthreads();
    #pragma unroll
    for (int ks = 0; ks < 2; ++ks) {
      bshort8 ah[2], al[2], bh2[2], bl2[2];
      #pragma unroll
      for (int f = 0; f < 2; ++f) {
        int rA = wm * 32 + f * 16 + fr;
        u32 oa = (u32)(rA * 128) + ((u32)((ks * 4 + gq) ^ (rA & 7)) << 4);
        ah[f] = *(const bshort8*)((const char*)sAh + oa);
        al[f] = *(const bshort8*)((const char*)sAl + oa);
        int rB = wn * 32 + f * 16 + fr;
        u32 ob = (u32)(rB * 128) + ((u32)((ks * 4 + gq) ^ (rB & 7)) << 4);
        bh2[f] = *(const bshort8*)((const char*)sBh + ob);
        bl2[f] = *(const bshort8*)((const char*)sBl + ob);
      }
      #pragma unroll
      for (int fi = 0; fi < 2; ++fi)
        #pragma unroll
        for (int fj = 0; fj < 2; ++fj) {
          acc[fi][fj] = __builtin_amdgcn_mfma_f32_16x16x32_bf16(ah[fi], bh2[fj], acc[fi][fj], 0, 0, 0);
          ac2[fi][fj] = __builtin_amdgcn_mfma_f32_16x16x32_bf16(ah[fi], bl2[fj], ac2[fi][fj], 0, 0, 0);
          ac2[fi][fj] = __builtin_amdgcn_mfma_f32_16x16x32_bf16(al[fi], bh2[fj], ac2[fi][fj], 0, 0, 0);
        }
    }
  }
  #pragma unroll
  for (int fi = 0; fi < 2; ++fi) {
    #pragma unroll
    for (int fj = 0; fj < 2; ++fj) {
      int col = col0 + wn * 32 + fj * 16 + fr;
      int rbase = row0 + wm * 32 + fi * 16 + gq * 4;
      #pragma unroll
      for (int r = 0; r < 4; ++r) {
        int row = rbase + r;
        if (row < M) {
          float vv = acc[fi][fj][r] + ac2[fi][fj][r];
          u32 bq = (u32)row / 257u;
          u32 sq = (u32)row - bq * 257u;
          Cf[((size_t)bq * 256 + col) * 257 + sq] = vv;
        }
      }
    }
  }
}

// ---------------- attention, cls query only (LN of cls row inline) ----------------
__global__ __launch_bounds__(256) void attn_cls(const float* __restrict__ T,
                                                const float* __restrict__ lngam,
                                                const float* __restrict__ lnbet,
                                                const float* __restrict__ wq,
                                                const float* __restrict__ Kb,
                                                const float* __restrict__ Vb,
                                                float* __restrict__ o_cls) {
  __shared__ float red[20];
  __shared__ float lred[8];
  int h = blockIdx.x, b = blockIdx.y;
  int tid = threadIdx.x, wid = tid >> 6, lane = tid & 63;
  // LN of cls row b*257
  float tv = T[((size_t)b * S) * D + tid];
  float s1 = wave_sum(tv);
  if (lane == 0) lred[wid] = s1;
  __syncthreads();
  float mu = ((lred[0] + lred[1]) + (lred[2] + lred[3])) * (1.0f / 256.0f);
  float dxv = tv - mu;
  float s2 = wave_sum(dxv * dxv);
  if (lane == 0) lred[4 + wid] = s2;
  __syncthreads();
  float var = ((lred[4] + lred[5]) + (lred[6] + lred[7])) * (1.0f / 256.0f);
  float rsd = 1.0f / sqrtf(var + 1e-5f);
  float xv = dxv * rsd * lngam[tid] + lnbet[tid];

  float part = xv * wq[h * 256 + tid];
  part = wave_sum(part);
  size_t rowbase = ((size_t)b * 256 + h) * 257;
  float kt = Kb[rowbase + tid], vt = Vb[rowbase + tid];
  float k2 = 0.f, v2 = 0.f;
  if (tid == 0) { k2 = Kb[rowbase + 256]; v2 = Vb[rowbase + 256]; }
  float lmax = tid == 0 ? fmaxf(kt, k2) : kt;
  float lmin = tid == 0 ? fminf(kt, k2) : kt;
  #pragma unroll
  for (int m = 1; m < 64; m <<= 1) {
    lmax = fmaxf(lmax, __shfl_xor(lmax, m, 64));
    lmin = fminf(lmin, __shfl_xor(lmin, m, 64));
  }
  if (lane == 0) { red[wid] = part; red[4 + wid] = lmax; red[8 + wid] = lmin; }
  __syncthreads();
  float q = (red[0] + red[1]) + (red[2] + red[3]);
  float kmax = fmaxf(fmaxf(red[4], red[5]), fmaxf(red[6], red[7]));
  float kmin = fminf(fminf(red[8], red[9]), fminf(red[10], red[11]));
  const float L2E = 1.4426950408889634f;
  float m = q >= 0.f ? q * kmax : q * kmin;
  float ql = q * L2E, nml = -m * L2E;
  float e = fexp2(fmaf(ql, kt, nml));
  float den = e, num = e * vt;
  if (tid == 0) {
    float e2 = fexp2(fmaf(ql, k2, nml));
    den += e2; num = fmaf(e2, v2, num);
  }
  den = wave_sum(den); num = wave_sum(num);
  if (lane == 0) { red[12 + wid] = den; red[16 + wid] = num; }
  __syncthreads();
  if (tid == 0) {
    float dd = (red[12] + red[13]) + (red[14] + red[15]);
    float nn = (red[16] + red[17]) + (red[18] + red[19]);
    o_cls[b * 256 + h] = nn / dd;
  }
}

// ====== TAIL: 5 launches (unchanged from R16) ======

__global__ __launch_bounds__(1024) void projln2_kernel(const float* __restrict__ o_cls,
                                                       const float* __restrict__ proj_w,
                                                       const float* __restrict__ proj_b,
                                                       const float* __restrict__ t,
                                                       const float* __restrict__ ln2_g,
                                                       const float* __restrict__ ln2_b,
                                                       float* __restrict__ tnbuf,
                                                       float* __restrict__ xn2) {
  __shared__ float orow[256];
  __shared__ float part[4][256];
  __shared__ float red[8];
  int b = blockIdx.x, tid = threadIdx.x;
  int nn = tid & 255, kq = tid >> 8;
  if (tid < 256) orow[tid] = o_cls[b * 256 + tid];
  __syncthreads();
  {
    const float* ob = orow + kq * 64;
    const float* wp = proj_w + (size_t)(kq * 64) * 256 + nn;
    float a0 = 0.f, a1 = 0.f, a2 = 0.f, a3 = 0.f;
    #pragma unroll
    for (int k = 0; k < 64; k += 4) {
      a0 = fmaf(ob[k + 0], wp[(size_t)(k + 0) * 256], a0);
      a1 = fmaf(ob[k + 1], wp[(size_t)(k + 1) * 256], a1);
      a2 = fmaf(ob[k + 2], wp[(size_t)(k + 2) * 256], a2);
      a3 = fmaf(ob[k + 3], wp[(size_t)(k + 3) * 256], a3);
    }
    part[kq][nn] = (a0 + a1) + (a2 + a3);
  }
  __syncthreads();
  float tval = 0.f;
  if (tid < 256) {
    tval = t[((size_t)b * S) * D + tid] + proj_b[tid] +
           ((part[0][tid] + part[1][tid]) + (part[2][tid] + part[3][tid]));
    tnbuf[b * 256 + tid] = tval;
    float s1 = wave_sum(tval);
    if ((tid & 63) == 0) red[tid >> 6] = s1;
  }
  __syncthreads();
  float mu = ((red[0] + red[1]) + (red[2] + red[3])) * (1.0f / 256.0f);
  if (tid < 256) {
    float dx = tval - mu;
    float s2 = wave_sum(dx * dx);
    if ((tid & 63) == 0) red[4 + (tid >> 6)] = s2;
  }
  __syncthreads();
  if (tid < 256) {
    float var = ((red[4] + red[5]) + (red[6] + red[7])) * (1.0f / 256.0f);
    float rs = 1.0f / sqrtf(var + 1e-5f);
    xn2[b * 256 + tid] = (tval - mu) * rs * ln2_g[tid] + ln2_b[tid];
  }
}

__global__ __launch_bounds__(256) void mlp1_part(const float* __restrict__ xn2,
                                                 const float* __restrict__ mlp_w1,
                                                 float* __restrict__ pB) {
  __shared__ float xs[8][32];
  int nc = blockIdx.x >> 3, kq = blockIdx.x & 7;
  int tid = threadIdx.x;
  {
    int b = tid >> 5, kk = tid & 31;
    xs[b][kk] = xn2[b * 256 + kq * 32 + kk];
  }
  __syncthreads();
  int n = nc * 256 + tid;
  const float* wp = mlp_w1 + (size_t)(kq * 32) * 1024 + n;
  float acc[8] = {0, 0, 0, 0, 0, 0, 0, 0};
  #pragma unroll
  for (int k = 0; k < 32; ++k) {
    float w = wp[(size_t)k * 1024];
    #pragma unroll
    for (int b = 0; b < 8; ++b) acc[b] = fmaf(xs[b][k], w, acc[b]);
  }
  #pragma unroll
  for (int b = 0; b < 8; ++b) pB[((size_t)kq * 8 + b) * 1024 + n] = acc[b];
}

__global__ __launch_bounds__(256) void mlp2_part(const float* __restrict__ pB,
                                                 const float* __restrict__ mlp_b1,
                                                 const float* __restrict__ mlp_w2,
                                                 float* __restrict__ pC) {
  __shared__ float hs[8][32];
  int kq = blockIdx.x;
  int tid = threadIdx.x;
  {
    int b = tid >> 5, kk = tid & 31;
    int n = kq * 32 + kk;
    float s = mlp_b1[n];
    #pragma unroll
    for (int q = 0; q < 8; ++q) s += pB[((size_t)q * 8 + b) * 1024 + n];
    hs[b][kk] = 0.5f * s * (1.0f + erff(s * 0.70710678118654752440f));
  }
  __syncthreads();
  int n = tid;
  const float* wp = mlp_w2 + (size_t)(kq * 32) * 256 + n;
  float acc[8] = {0, 0, 0, 0, 0, 0, 0, 0};
  #pragma unroll
  for (int k = 0; k < 32; ++k) {
    float w = wp[(size_t)k * 256];
    #pragma unroll
    for (int b = 0; b < 8; ++b) acc[b] = fmaf(hs[b][k], w, acc[b]);
  }
  #pragma unroll
  for (int b = 0; b < 8; ++b) pC[((size_t)kq * 8 + b) * 256 + n] = acc[b];
}

__global__ __launch_bounds__(256) void head_part(const float* __restrict__ pC,
                                                 const float* __restrict__ mlp_b2,
                                                 const float* __restrict__ tnbuf,
                                                 const float* __restrict__ head_w,
                                                 float* __restrict__ pD) {
  __shared__ float ts[8][32];
  int nc = blockIdx.x >> 3, kq = blockIdx.x & 7;
  int tid = threadIdx.x;
  {
    int b = tid >> 5, kk = tid & 31;
    int d = kq * 32 + kk;
    float s = tnbuf[b * 256 + d] + mlp_b2[d];
    #pragma unroll
    for (int q = 0; q < 32; ++q) s += pC[((size_t)q * 8 + b) * 256 + d];
    ts[b][kk] = s;
  }
  __syncthreads();
  int nn = tid & 127, dq = tid >> 7;          // dq in {0,1}
  int n = nc * 128 + nn;
  bool valid = n < NCLS;
  const float* wp = head_w + (size_t)(kq * 32 + dq * 16) * NCLS + n;
  float acc[8] = {0, 0, 0, 0, 0, 0, 0, 0};
  #pragma unroll
  for (int k = 0; k < 16; ++k) {
    float w = valid ? wp[(size_t)k * NCLS] : 0.f;
    int kk = dq * 16 + k;
    #pragma unroll
    for (int b = 0; b < 8; ++b) acc[b] = fmaf(ts[b][kk], w, acc[b]);
  }
  #pragma unroll
  for (int b = 0; b < 8; ++b)
    pD[(((size_t)(kq * 2 + dq)) * 8 + b) * 1024 + n] = acc[b];
}

__global__ __launch_bounds__(256) void softmax_kernel(const float* __restrict__ pD,
                                                      const float* __restrict__ head_b,
                                                      float* __restrict__ out) {
  __shared__ float red[8];
  int b = blockIdx.x, tid = threadIdx.x;
  int wid = tid >> 6, lane = tid & 63;
  float v[4];
  #pragma unroll
  for (int i = 0; i < 4; ++i) {
    int n = i * 256 + tid;
    if (n < NCLS) {
      float s = head_b[n];
      #pragma unroll
      for (int q = 0; q < 16; ++q) s += pD[((size_t)q * 8 + b) * 1024 + n];
      v[i] = s;
    } else {
      v[i] = -1e30f;
    }
  }
  float mx = fmaxf(fmaxf(v[0], v[1]), fmaxf(v[2], v[3]));
  #pragma unroll
  for (int s = 1; s < 64; s <<= 1) mx = fmaxf(mx, __shfl_xor(mx, s, 64));
  if (lane == 0) red[wid] = mx;
  __syncthreads();
  float gmax = fmaxf(fmaxf(red[0], red[1]), fmaxf(red[2], red[3]));
  float e[4], ssum = 0.f;
  #pragma unroll
  for (int i = 0; i < 4; ++i) {
    e[i] = expf(v[i] - gmax);
    if (i * 256 + tid >= NCLS) e[i] = 0.f;
    ssum += e[i];
  }
  ssum = wave_sum(ssum);
  if (lane == 0) red[4 + wid] = ssum;
  __syncthreads();
  float inv = 1.0f / ((red[4] + red[5]) + (red[6] + red[7]));
  #pragma unroll
  for (int i = 0; i < 4; ++i) {
    int n = i * 256 + tid;
    if (n < NCLS) out[(size_t)b * NCLS + n] = e[i] * inv;
  }
}

// ---------------- launch ----------------
extern "C" void kernel_launch(void* const* d_in, const int* in_sizes, int n_in,
                              void* d_out, int out_size, void* d_ws, size_t ws_size,
                              hipStream_t stream) {
  const float* x        = (const float*)d_in[0];
  const float* class_tk = (const float*)d_in[1];
  const float* pos_emb  = (const float*)d_in[2];
  const float* patch_w  = (const float*)d_in[3];
  const float* patch_b  = (const float*)d_in[4];
  const float* wq       = (const float*)d_in[5];
  const float* wk       = (const float*)d_in[6];
  const float* wv       = (const float*)d_in[7];
  const float* proj_w   = (const float*)d_in[8];
  const float* proj_b   = (const float*)d_in[9];
  const float* mlp_w1   = (const float*)d_in[10];
  const float* mlp_b1   = (const float*)d_in[11];
  const float* mlp_w2   = (const float*)d_in[12];
  const float* mlp_b2   = (const float*)d_in[13];
  const float* ln1_g    = (const float*)d_in[14];
  const float* ln1_b    = (const float*)d_in[15];
  const float* ln2_g    = (const float*)d_in[16];
  const float* ln2_b    = (const float*)d_in[17];
  const float* head_w   = (const float*)d_in[18];
  const float* head_b   = (const float*)d_in[19];
  float* out = (float*)d_out;

  float* ws = (float*)d_ws;
  const size_t NTOK = (size_t)M_ROWS * D;   // 526336
  float* t     = ws;                            // [2056][256] fp32
  float* kk    = ws + 2 * NTOK;                 // K transposed [b][h][s]
  float* v     = ws + 3 * NTOK;                 // V transposed
  float* ocls  = ws + 4 * NTOK;                 // [8][256]
  u16*  Wkv    = (u16*)(ws + 4 * NTOK + 4096);  // kh,kl,vh,vl (4*65536 u16)
  float* TAIL  = ws + 5 * NTOK;
  float* tnbuf = TAIL;                 // [8][256]
  float* xn2   = TAIL + 2048;          // [8][256]
  float* pB    = TAIL + 4096;          // [8][8][1024]  = 65536
  float* pC    = pB + 65536;           // [32][8][256]  = 65536
  float* pD    = pC + 65536;           // [16][8][1024] = 131072

  stage0<<<1359, 256, 0, stream>>>(x, patch_w, patch_b, pos_emb, class_tk,
                                   wk, wv, proj_w, mlp_w1, mlp_w2, head_w, Wkv, t);

  kv_ln_kernel<<<dim3(4, 33, 2), 256, 0, stream>>>(t, ln1_g, ln1_b, Wkv, kk, v);

  attn_cls<<<dim3(256, Bsz), 256, 0, stream>>>(t, ln1_g, ln1_b, wq, kk, v, ocls);

  projln2_kernel<<<Bsz, 1024, 0, stream>>>(ocls, proj_w, proj_b, t, ln2_g, ln2_b, tnbuf, xn2);

  mlp1_part<<<32, 256, 0, stream>>>(xn2, mlp_w1, pB);

  mlp2_part<<<32, 256, 0, stream>>>(pB, mlp_b1, mlp_w2, pC);

  head_part<<<64, 256, 0, stream>>>(pC, mlp_b2, tnbuf, head_w, pD);

  softmax_kernel<<<Bsz, 256, 0, stream>>>(pD, head_b, out);
}

// Round 18
// 62.026 us; speedup vs baseline: 1.2115x; 1.2115x over previous
//
#include <hip/hip_runtime.h>
#include <math.h>

// ---------------- constants ----------------
#define Bsz   8
#define D     256      // d_model = num_heads = num_patches = 256
#define S     257      // seq len
#define MLP   1024
#define NCLS  1000
#define M_ROWS (Bsz * S)   // 2056

typedef unsigned int u32;
typedef unsigned short u16;
typedef __attribute__((ext_vector_type(8))) short bshort8;
typedef __attribute__((ext_vector_type(4))) float f32x4;

__device__ __forceinline__ float wave_sum(float v) {
  #pragma unroll
  for (int m = 1; m < 64; m <<= 1) v += __shfl_xor(v, m, 64);
  return v;
}

__device__ __forceinline__ u16 f2bf(float f) {
  u32 u = __float_as_uint(f);
  u += 0x7FFFu + ((u >> 16) & 1u);   // RNE
  return (u16)(u >> 16);
}
__device__ __forceinline__ float bf2f(u16 h) { return __uint_as_float(((u32)h) << 16); }
__device__ __forceinline__ u32 pk2(u16 a, u16 b) { return (u32)a | ((u32)b << 16); }
__device__ __forceinline__ float fexp2(float x) { return __builtin_amdgcn_exp2f(x); }

// ---------------- patch embed body (MFMA mini-GEMM, cls fused) ----------------
__device__ __forceinline__ void patch_body(int blk, int tid,
                                           const float* __restrict__ x,
                                           const float* __restrict__ pw,
                                           const float* __restrict__ pb,
                                           const float* __restrict__ pos,
                                           const float* __restrict__ ct,
                                           float* __restrict__ t,
                                           char* smem) {
  u16* sAh = (u16*)smem;
  u16* sAl = (u16*)(smem + 8192);
  u16* sBh = (u16*)(smem + 16384);
  u16* sBl = (u16*)(smem + 24576);
  const int n = blk >> 2;
  const int col0 = (blk & 3) * 64;
  const int pi = n >> 4, pj = n & 15;
  const int lane = tid & 63;
  const int w = tid >> 6;
  const int fr = lane & 15, g = lane >> 4;
  const int sr = tid >> 2, sc = tid & 3;
  const int arow = sr > 7 ? 7 : sr;   // M=8, clamp
  const u32 off0 = (u32)(sr * 128) + ((u32)((2 * sc)     ^ (sr & 7)) << 4);
  const u32 off1 = (u32)(sr * 128) + ((u32)((2 * sc + 1) ^ (sr & 7)) << 4);
  const float* ap32 = x + (size_t)arow * 65536 + (size_t)(pi * 16) * 256 + pj * 16;
  const float* bp32 = pw + (size_t)(col0 + sr) * 65536 + (size_t)n * 256 + sc * 16;

  if ((blk & 3) == 0 && tid < 8)
    t[((size_t)tid * S) * D + n] = ct[n] + pos[n];

  f32x4 acc = {0, 0, 0, 0}, ac2 = {0, 0, 0, 0};

  for (int k0 = 0; k0 < 256; k0 += 64) {
    const float* asrc = ap32 + (size_t)((k0 >> 4) + sc) * 256;
    float fa[16], fb[16];
    #pragma unroll
    for (int i = 0; i < 4; ++i) {
      float4 f4 = *(const float4*)(asrc + i * 4);
      fa[i*4+0] = f4.x; fa[i*4+1] = f4.y; fa[i*4+2] = f4.z; fa[i*4+3] = f4.w;
      float4 g4 = *(const float4*)(bp32 + k0 + i * 4);
      fb[i*4+0] = g4.x; fb[i*4+1] = g4.y; fb[i*4+2] = g4.z; fb[i*4+3] = g4.w;
    }
    u16 ah16[16], al16[16], bh16[16], bl16[16];
    #pragma unroll
    for (int i = 0; i < 16; ++i) {
      u16 h = f2bf(fa[i]); ah16[i] = h; al16[i] = f2bf(fa[i] - bf2f(h));
      u16 hb = f2bf(fb[i]); bh16[i] = hb; bl16[i] = f2bf(fb[i] - bf2f(hb));
    }
    __syncthreads();
    *(uint4*)((char*)sAh + off0) = make_uint4(pk2(ah16[0],ah16[1]), pk2(ah16[2],ah16[3]), pk2(ah16[4],ah16[5]), pk2(ah16[6],ah16[7]));
    *(uint4*)((char*)sAh + off1) = make_uint4(pk2(ah16[8],ah16[9]), pk2(ah16[10],ah16[11]), pk2(ah16[12],ah16[13]), pk2(ah16[14],ah16[15]));
    *(uint4*)((char*)sAl + off0) = make_uint4(pk2(al16[0],al16[1]), pk2(al16[2],al16[3]), pk2(al16[4],al16[5]), pk2(al16[6],al16[7]));
    *(uint4*)((char*)sAl + off1) = make_uint4(pk2(al16[8],al16[9]), pk2(al16[10],al16[11]), pk2(al16[12],al16[13]), pk2(al16[14],al16[15]));
    *(uint4*)((char*)sBh + off0) = make_uint4(pk2(bh16[0],bh16[1]), pk2(bh16[2],bh16[3]), pk2(bh16[4],bh16[5]), pk2(bh16[6],bh16[7]));
    *(uint4*)((char*)sBh + off1) = make_uint4(pk2(bh16[8],bh16[9]), pk2(bh16[10],bh16[11]), pk2(bh16[12],bh16[13]), pk2(bh16[14],bh16[15]));
    *(uint4*)((char*)sBl + off0) = make_uint4(pk2(bl16[0],bl16[1]), pk2(bl16[2],bl16[3]), pk2(bl16[4],bl16[5]), pk2(bl16[6],bl16[7]));
    *(uint4*)((char*)sBl + off1) = make_uint4(pk2(bl16[8],bl16[9]), pk2(bl16[10],bl16[11]), pk2(bl16[12],bl16[13]), pk2(bl16[14],bl16[15]));
    __syncthreads();
    #pragma unroll
    for (int ks = 0; ks < 2; ++ks) {
      int rA = fr;
      u32 oa = (u32)(rA * 128) + ((u32)((ks * 4 + g) ^ (rA & 7)) << 4);
      bshort8 ah = *(const bshort8*)((const char*)sAh + oa);
      bshort8 al = *(const bshort8*)((const char*)sAl + oa);
      int rB = w * 16 + fr;
      u32 ob = (u32)(rB * 128) + ((u32)((ks * 4 + g) ^ (rB & 7)) << 4);
      bshort8 bh = *(const bshort8*)((const char*)sBh + ob);
      bshort8 bl = *(const bshort8*)((const char*)sBl + ob);
      acc = __builtin_amdgcn_mfma_f32_16x16x32_bf16(ah, bh, acc, 0, 0, 0);
      ac2 = __builtin_amdgcn_mfma_f32_16x16x32_bf16(ah, bl, ac2, 0, 0, 0);
      ac2 = __builtin_amdgcn_mfma_f32_16x16x32_bf16(al, bh, ac2, 0, 0, 0);
    }
  }
  if (g < 2) {
    int h = col0 + w * 16 + fr;
    float addend = pb[h * 256 + n] + pos[(1 + h) * 256 + n];
    #pragma unroll
    for (int r = 0; r < 4; ++r) {
      int b = g * 4 + r;
      t[((size_t)b * S + 1 + h) * D + n] = acc[r] + ac2[r] + addend;
    }
  }
}

// K/V weight split-convert
__device__ __forceinline__ void conv_copy2_body(int blk, int tid,
                                                const float* __restrict__ wk,
                                                const float* __restrict__ wv,
                                                u16* __restrict__ W) {
  int wsel = blk >> 6, tile = blk & 63;
  const float* src = wsel == 0 ? wk : wv;
  u16* oh = W + wsel * 131072;
  u16* ol = oh + 65536;
  int r0 = (tile >> 3) * 32, c0 = (tile & 7) * 32;
  int tr = tid >> 3, tc = (tid & 7) * 4;
  const float4 f = *(const float4*)(src + (size_t)(r0 + tr) * 256 + c0 + tc);
  u16 h0 = f2bf(f.x), h1 = f2bf(f.y), h2 = f2bf(f.z), h3 = f2bf(f.w);
  u16 l0 = f2bf(f.x - bf2f(h0)), l1 = f2bf(f.y - bf2f(h1));
  u16 l2 = f2bf(f.z - bf2f(h2)), l3 = f2bf(f.w - bf2f(h3));
  size_t o = (size_t)(r0 + tr) * 256 + c0 + tc;
  *(uint2*)(oh + o) = make_uint2(pk2(h0, h1), pk2(h2, h3));
  *(uint2*)(ol + o) = make_uint2(pk2(l0, l1), pk2(l2, l3));
}

// prefetch weights into L2/L3 (keeps loads live via asm)
__device__ __forceinline__ void prefetch_body(int blk, int tid,
                                              const float* __restrict__ p, int nfloat) {
  int base = blk * 4096 + tid * 4;
  float acc = 0.f;
  #pragma unroll
  for (int i = 0; i < 4; ++i) {
    int idx = base + i * 1024;
    if (idx + 3 < nfloat) {
      float4 f = *(const float4*)(p + idx);
      acc += (f.x + f.y) + (f.z + f.w);
    }
  }
  asm volatile("" :: "v"(acc));
}

// stage0: patch (0..1023) + K/V weight conv (1024..1151) + tail-weight L3 prefetch
__global__ __launch_bounds__(256) void stage0(const float* __restrict__ x,
                                              const float* __restrict__ pw,
                                              const float* __restrict__ pb,
                                              const float* __restrict__ pos,
                                              const float* __restrict__ ct,
                                              const float* __restrict__ wk,
                                              const float* __restrict__ wv,
                                              const float* __restrict__ proj_w,
                                              const float* __restrict__ mlp_w1,
                                              const float* __restrict__ mlp_w2,
                                              const float* __restrict__ head_w,
                                              u16* __restrict__ Wkv,
                                              float* __restrict__ t) {
  __shared__ __align__(16) char smem[32768];
  int blk = blockIdx.x, tid = threadIdx.x;
  if (blk < 1024)      patch_body(blk, tid, x, pw, pb, pos, ct, t, smem);
  else if (blk < 1152) conv_copy2_body(blk - 1024, tid, wk, wv, Wkv);
  else {
    int p = blk - 1152;
    if (p < 16)       prefetch_body(p, tid, proj_w, 65536);
    else if (p < 80)  prefetch_body(p - 16, tid, mlp_w1, 262144);
    else if (p < 144) prefetch_body(p - 80, tid, mlp_w2, 262144);
    else              prefetch_body(p - 144, tid, head_w, 256000);
  }
}

// ---------------- layernorm -> split bf16 planes ----------------
__global__ __launch_bounds__(256) void ln_split(const float* __restrict__ in,
                                                u16* __restrict__ oh,
                                                u16* __restrict__ ol,
                                                const float* __restrict__ g,
                                                const float* __restrict__ b,
                                                int nrows) {
  int wid = threadIdx.x >> 6, lane = threadIdx.x & 63;
  int row = blockIdx.x * 4 + wid;
  if (row >= nrows) return;
  const float* p = in + (size_t)row * D;
  float4 v = *(const float4*)&p[lane * 4];
  float s = wave_sum(v.x + v.y + v.z + v.w);
  float mu = s * (1.0f / 256.0f);
  float dx = v.x - mu, dy = v.y - mu, dz = v.z - mu, dw = v.w - mu;
  float q = wave_sum(dx * dx + dy * dy + dz * dz + dw * dw);
  float rs = 1.0f / sqrtf(q * (1.0f / 256.0f) + 1e-5f);
  float4 gv = *(const float4*)&g[lane * 4];
  float4 bv = *(const float4*)&b[lane * 4];
  float o0 = dx * rs * gv.x + bv.x;
  float o1 = dy * rs * gv.y + bv.y;
  float o2 = dz * rs * gv.z + bv.z;
  float o3 = dw * rs * gv.w + bv.w;
  u16 h0 = f2bf(o0), h1 = f2bf(o1), h2 = f2bf(o2), h3 = f2bf(o3);
  u16 l0 = f2bf(o0 - bf2f(h0)), l1 = f2bf(o1 - bf2f(h1));
  u16 l2 = f2bf(o2 - bf2f(h2)), l3 = f2bf(o3 - bf2f(h3));
  size_t o = (size_t)row * D + lane * 4;
  *(uint2*)(oh + o) = make_uint2(pk2(h0, h1), pk2(h2, h3));
  *(uint2*)(ol + o) = make_uint2(pk2(l0, l1), pk2(l2, l3));
}

// ---------------- MFMA split-bf16 GEMM core ----------------
template<int OUTT>
__device__ __forceinline__ void gemm_core(const u16* __restrict__ A16,
                                          const u16* __restrict__ A16l,
                                          const u16* __restrict__ Bh,
                                          const u16* __restrict__ Bl,
                                          float* __restrict__ Cf,
                                          int M, int N, int K, int row0, int col0) {
  __shared__ __align__(16) u16 sAh[4096];
  __shared__ __align__(16) u16 sAl[4096];
  __shared__ __align__(16) u16 sBh[4096];
  __shared__ __align__(16) u16 sBl[4096];
  const int tid = threadIdx.x;
  const int lane = tid & 63;
  const int w = tid >> 6, wm = w >> 1, wn = w & 1;
  const int fr = lane & 15, g = lane >> 4;
  const int sr = tid >> 2, sc = tid & 3;
  int arow = row0 + sr; if (arow > M - 1) arow = M - 1;
  const u32 off0 = (u32)(sr * 128) + ((u32)((2 * sc)     ^ (sr & 7)) << 4);
  const u32 off1 = (u32)(sr * 128) + ((u32)((2 * sc + 1) ^ (sr & 7)) << 4);
  const u16* ap16  = A16  + (size_t)arow * K + sc * 16;
  const u16* ap16l = A16l + (size_t)arow * K + sc * 16;
  const u16* bhp = Bh + (size_t)(col0 + sr) * K + sc * 16;
  const u16* blp = Bl + (size_t)(col0 + sr) * K + sc * 16;

  f32x4 acc[2][2], ac2[2][2];
  #pragma unroll
  for (int i = 0; i < 2; ++i)
    #pragma unroll
    for (int j = 0; j < 2; ++j) { acc[i][j] = (f32x4){0,0,0,0}; ac2[i][j] = (f32x4){0,0,0,0}; }

  for (int k0 = 0; k0 < K; k0 += 64) {
    uint4 wAh0 = *(const uint4*)(ap16 + k0);
    uint4 wAh1 = *(const uint4*)(ap16 + k0 + 8);
    uint4 wAl0 = *(const uint4*)(ap16l + k0);
    uint4 wAl1 = *(const uint4*)(ap16l + k0 + 8);
    uint4 wBh0 = *(const uint4*)(bhp + k0);
    uint4 wBh1 = *(const uint4*)(bhp + k0 + 8);
    uint4 wBl0 = *(const uint4*)(blp + k0);
    uint4 wBl1 = *(const uint4*)(blp + k0 + 8);
    __syncthreads();
    *(uint4*)((char*)sAh + off0) = wAh0;
    *(uint4*)((char*)sAh + off1) = wAh1;
    *(uint4*)((char*)sAl + off0) = wAl0;
    *(uint4*)((char*)sAl + off1) = wAl1;
    *(uint4*)((char*)sBh + off0) = wBh0;
    *(uint4*)((char*)sBh + off1) = wBh1;
    *(uint4*)((char*)sBl + off0) = wBl0;
    *(uint4*)((char*)sBl + off1) = wBl1;
    __syncthreads();
    #pragma unroll
    for (int ks = 0; ks < 2; ++ks) {
      bshort8 ah[2], al[2], bh2[2], bl2[2];
      #pragma unroll
      for (int f = 0; f < 2; ++f) {
        int rA = wm * 32 + f * 16 + fr;
        u32 oa = (u32)(rA * 128) + ((u32)((ks * 4 + g) ^ (rA & 7)) << 4);
        ah[f] = *(const bshort8*)((const char*)sAh + oa);
        al[f] = *(const bshort8*)((const char*)sAl + oa);
        int rB = wn * 32 + f * 16 + fr;
        u32 ob = (u32)(rB * 128) + ((u32)((ks * 4 + g) ^ (rB & 7)) << 4);
        bh2[f] = *(const bshort8*)((const char*)sBh + ob);
        bl2[f] = *(const bshort8*)((const char*)sBl + ob);
      }
      #pragma unroll
      for (int fi = 0; fi < 2; ++fi)
        #pragma unroll
        for (int fj = 0; fj < 2; ++fj) {
          acc[fi][fj] = __builtin_amdgcn_mfma_f32_16x16x32_bf16(ah[fi], bh2[fj], acc[fi][fj], 0, 0, 0);
          ac2[fi][fj] = __builtin_amdgcn_mfma_f32_16x16x32_bf16(ah[fi], bl2[fj], ac2[fi][fj], 0, 0, 0);
          ac2[fi][fj] = __builtin_amdgcn_mfma_f32_16x16x32_bf16(al[fi], bh2[fj], ac2[fi][fj], 0, 0, 0);
        }
    }
  }
  #pragma unroll
  for (int fi = 0; fi < 2; ++fi) {
    #pragma unroll
    for (int fj = 0; fj < 2; ++fj) {
      int col = col0 + wn * 32 + fj * 16 + fr;
      int rbase = row0 + wm * 32 + fi * 16 + g * 4;
      #pragma unroll
      for (int r = 0; r < 4; ++r) {
        int row = rbase + r;
        if (row < M) {
          float v = acc[fi][fj][r] + ac2[fi][fj][r];
          if (OUTT) {
            u32 bq = (u32)row / 257u;
            u32 sq = (u32)row - bq * 257u;
            Cf[((size_t)bq * 256 + col) * 257 + sq] = v;
          } else {
            Cf[(size_t)row * N + col] = v;
          }
        }
      }
    }
  }
}

__global__ __launch_bounds__(256) void kv_kernel(const u16* __restrict__ xnh,
                                                 const u16* __restrict__ xnl,
                                                 const u16* __restrict__ Wkv,
                                                 float* __restrict__ kk,
                                                 float* __restrict__ v) {
  int z = blockIdx.z;
  const u16* Bh = Wkv + z * 131072;
  const u16* Bl = Bh + 65536;
  float* C = z == 0 ? kk : v;
  gemm_core<1>(xnh, xnl, Bh, Bl, C, M_ROWS, 256, 256, blockIdx.y * 64, blockIdx.x * 64);
}

// ---------------- attention, cls query only: o_cls[b][h] ----------------
__global__ __launch_bounds__(256) void attn_cls(const u16* __restrict__ xnh,
                                                const u16* __restrict__ xnl,
                                                const float* __restrict__ wq,
                                                const float* __restrict__ Kb,
                                                const float* __restrict__ Vb,
                                                float* __restrict__ o_cls) {
  __shared__ float red[20];
  int h = blockIdx.x, b = blockIdx.y;
  int tid = threadIdx.x, wid = tid >> 6, lane = tid & 63;
  size_t xbase = (size_t)b * 257 * 256;
  float xv = bf2f(xnh[xbase + tid]) + bf2f(xnl[xbase + tid]);
  float part = xv * wq[h * 256 + tid];
  part = wave_sum(part);
  size_t rowbase = ((size_t)b * 256 + h) * 257;
  float kt = Kb[rowbase + tid], vt = Vb[rowbase + tid];
  float k2 = 0.f, v2 = 0.f;
  if (tid == 0) { k2 = Kb[rowbase + 256]; v2 = Vb[rowbase + 256]; }
  float lmax = tid == 0 ? fmaxf(kt, k2) : kt;
  float lmin = tid == 0 ? fminf(kt, k2) : kt;
  #pragma unroll
  for (int m = 1; m < 64; m <<= 1) {
    lmax = fmaxf(lmax, __shfl_xor(lmax, m, 64));
    lmin = fminf(lmin, __shfl_xor(lmin, m, 64));
  }
  if (lane == 0) { red[wid] = part; red[4 + wid] = lmax; red[8 + wid] = lmin; }
  __syncthreads();
  float q = (red[0] + red[1]) + (red[2] + red[3]);
  float kmax = fmaxf(fmaxf(red[4], red[5]), fmaxf(red[6], red[7]));
  float kmin = fminf(fminf(red[8], red[9]), fminf(red[10], red[11]));
  const float L2E = 1.4426950408889634f;
  float m = q >= 0.f ? q * kmax : q * kmin;
  float ql = q * L2E, nml = -m * L2E;
  float e = fexp2(fmaf(ql, kt, nml));
  float den = e, num = e * vt;
  if (tid == 0) {
    float e2 = fexp2(fmaf(ql, k2, nml));
    den += e2; num = fmaf(e2, v2, num);
  }
  den = wave_sum(den); num = wave_sum(num);
  if (lane == 0) { red[12 + wid] = den; red[16 + wid] = num; }
  __syncthreads();
  if (tid == 0) {
    float dd = (red[12] + red[13]) + (red[14] + red[15]);
    float nn = (red[16] + red[17]) + (red[18] + red[19]);
    o_cls[b * 256 + h] = nn / dd;
  }
}

// ====== TAIL (R11 structure, reduce kernels folded into consumers) ======

// T1: proj partials. grid 64 = (b<<3)|kq ; thread n = tid; 32 loads.
__global__ __launch_bounds__(256) void proj_part(const float* __restrict__ o_cls,
                                                 const float* __restrict__ proj_w,
                                                 float* __restrict__ pA) {
  int b = blockIdx.x >> 3, kq = blockIdx.x & 7;
  int n = threadIdx.x;
  const float* ob = o_cls + b * 256 + kq * 32;
  const float* wp = proj_w + (size_t)(kq * 32) * 256 + n;
  float a0 = 0.f, a1 = 0.f, a2 = 0.f, a3 = 0.f;
  #pragma unroll
  for (int k = 0; k < 32; k += 4) {
    a0 = fmaf(ob[k + 0], wp[(size_t)(k + 0) * 256], a0);
    a1 = fmaf(ob[k + 1], wp[(size_t)(k + 1) * 256], a1);
    a2 = fmaf(ob[k + 2], wp[(size_t)(k + 2) * 256], a2);
    a3 = fmaf(ob[k + 3], wp[(size_t)(k + 3) * 256], a3);
  }
  pA[((size_t)kq * 8 + b) * 256 + n] = (a0 + a1) + (a2 + a3);
}

// T2: reduce pA + bias + residual -> tnbuf; LN -> xn2. grid 8 = b.
__global__ __launch_bounds__(256) void proj_red_ln(const float* __restrict__ pA,
                                                   const float* __restrict__ proj_b,
                                                   const float* __restrict__ t,
                                                   const float* __restrict__ ln2_g,
                                                   const float* __restrict__ ln2_b,
                                                   float* __restrict__ tnbuf,
                                                   float* __restrict__ xn2) {
  __shared__ float red[8];
  int b = blockIdx.x, n = threadIdx.x;
  int wid = n >> 6, lane = n & 63;
  float s = t[((size_t)b * S) * D + n] + proj_b[n];
  #pragma unroll
  for (int kq = 0; kq < 8; ++kq) s += pA[((size_t)kq * 8 + b) * 256 + n];
  tnbuf[b * 256 + n] = s;
  float s1 = wave_sum(s);
  if (lane == 0) red[wid] = s1;
  __syncthreads();
  float mu = ((red[0] + red[1]) + (red[2] + red[3])) * (1.0f / 256.0f);
  float dx = s - mu;
  float s2 = wave_sum(dx * dx);
  if (lane == 0) red[4 + wid] = s2;
  __syncthreads();
  float var = ((red[4] + red[5]) + (red[6] + red[7])) * (1.0f / 256.0f);
  float rs = 1.0f / sqrtf(var + 1e-5f);
  xn2[b * 256 + n] = dx * rs * ln2_g[n] + ln2_b[n];
}

// T3: mlp1 partials, b-amortized. grid 32 = (nc<<3)|kq (nc 0..3); 32 loads x 8b.
__global__ __launch_bounds__(256) void mlp1_part(const float* __restrict__ xn2,
                                                 const float* __restrict__ mlp_w1,
                                                 float* __restrict__ pB) {
  __shared__ float xs[8][32];
  int nc = blockIdx.x >> 3, kq = blockIdx.x & 7;
  int tid = threadIdx.x;
  {
    int b = tid >> 5, kk = tid & 31;
    xs[b][kk] = xn2[b * 256 + kq * 32 + kk];
  }
  __syncthreads();
  int n = nc * 256 + tid;
  const float* wp = mlp_w1 + (size_t)(kq * 32) * 1024 + n;
  float acc[8] = {0, 0, 0, 0, 0, 0, 0, 0};
  #pragma unroll
  for (int k = 0; k < 32; ++k) {
    float w = wp[(size_t)k * 1024];
    #pragma unroll
    for (int b = 0; b < 8; ++b) acc[b] = fmaf(xs[b][k], w, acc[b]);
  }
  #pragma unroll
  for (int b = 0; b < 8; ++b) pB[((size_t)kq * 8 + b) * 1024 + n] = acc[b];
}

// T4: mlp2 partials, pB-reduce + bias + gelu folded. grid 32 = kq; 32+8 loads x 8b.
__global__ __launch_bounds__(256) void mlp2_part(const float* __restrict__ pB,
                                                 const float* __restrict__ mlp_b1,
                                                 const float* __restrict__ mlp_w2,
                                                 float* __restrict__ pC) {
  __shared__ float hs[8][32];
  int kq = blockIdx.x;
  int tid = threadIdx.x;
  {
    // hs[b][kk] = gelu(b1[n] + sum_q pB[q][b][n]),  n = kq*32+kk
    int b = tid >> 5, kk = tid & 31;
    int n = kq * 32 + kk;
    float s = mlp_b1[n];
    #pragma unroll
    for (int q = 0; q < 8; ++q) s += pB[((size_t)q * 8 + b) * 1024 + n];
    hs[b][kk] = 0.5f * s * (1.0f + erff(s * 0.70710678118654752440f));
  }
  __syncthreads();
  int n = tid;
  const float* wp = mlp_w2 + (size_t)(kq * 32) * 256 + n;
  float acc[8] = {0, 0, 0, 0, 0, 0, 0, 0};
  #pragma unroll
  for (int k = 0; k < 32; ++k) {
    float w = wp[(size_t)k * 256];
    #pragma unroll
    for (int b = 0; b < 8; ++b) acc[b] = fmaf(hs[b][k], w, acc[b]);
  }
  #pragma unroll
  for (int b = 0; b < 8; ++b) pC[((size_t)kq * 8 + b) * 256 + n] = acc[b];
}

// T5: head partials, pC-reduce + bias + residual folded. grid 64 = (nc<<3)|kq.
__global__ __launch_bounds__(256) void head_part(const float* __restrict__ pC,
                                                 const float* __restrict__ mlp_b2,
                                                 const float* __restrict__ tnbuf,
                                                 const float* __restrict__ head_w,
                                                 float* __restrict__ pD) {
  __shared__ float ts[8][32];
  int nc = blockIdx.x >> 3, kq = blockIdx.x & 7;
  int tid = threadIdx.x;
  {
    // ts[b][kk] = tnbuf[b][d] + b2[d] + sum_q pC[q][b][d],  d = kq*32+kk
    int b = tid >> 5, kk = tid & 31;
    int d = kq * 32 + kk;
    float s = tnbuf[b * 256 + d] + mlp_b2[d];
    #pragma unroll
    for (int q = 0; q < 32; ++q) s += pC[((size_t)q * 8 + b) * 256 + d];
    ts[b][kk] = s;
  }
  __syncthreads();
  int nn = tid & 127, dq = tid >> 7;          // dq in {0,1}
  int n = nc * 128 + nn;
  bool valid = n < NCLS;
  const float* wp = head_w + (size_t)(kq * 32 + dq * 16) * NCLS + n;
  float acc[8] = {0, 0, 0, 0, 0, 0, 0, 0};
  #pragma unroll
  for (int k = 0; k < 16; ++k) {
    float w = valid ? wp[(size_t)k * NCLS] : 0.f;
    int kk = dq * 16 + k;
    #pragma unroll
    for (int b = 0; b < 8; ++b) acc[b] = fmaf(ts[b][kk], w, acc[b]);
  }
  #pragma unroll
  for (int b = 0; b < 8; ++b)
    pD[(((size_t)(kq * 2 + dq)) * 8 + b) * 1024 + n] = acc[b];
}

// T6: reduce pD + head bias -> logits; softmax. grid 8 = b.
__global__ __launch_bounds__(256) void softmax_kernel(const float* __restrict__ pD,
                                                      const float* __restrict__ head_b,
                                                      float* __restrict__ out) {
  __shared__ float red[8];
  int b = blockIdx.x, tid = threadIdx.x;
  int wid = tid >> 6, lane = tid & 63;
  float v[4];
  #pragma unroll
  for (int i = 0; i < 4; ++i) {
    int n = i * 256 + tid;
    if (n < NCLS) {
      float s = head_b[n];
      #pragma unroll
      for (int q = 0; q < 16; ++q) s += pD[((size_t)q * 8 + b) * 1024 + n];
      v[i] = s;
    } else {
      v[i] = -1e30f;
    }
  }
  float mx = fmaxf(fmaxf(v[0], v[1]), fmaxf(v[2], v[3]));
  #pragma unroll
  for (int s = 1; s < 64; s <<= 1) mx = fmaxf(mx, __shfl_xor(mx, s, 64));
  if (lane == 0) red[wid] = mx;
  __syncthreads();
  float gmax = fmaxf(fmaxf(red[0], red[1]), fmaxf(red[2], red[3]));
  float e[4], ssum = 0.f;
  #pragma unroll
  for (int i = 0; i < 4; ++i) {
    e[i] = expf(v[i] - gmax);
    if (i * 256 + tid >= NCLS) e[i] = 0.f;
    ssum += e[i];
  }
  ssum = wave_sum(ssum);
  if (lane == 0) red[4 + wid] = ssum;
  __syncthreads();
  float inv = 1.0f / ((red[4] + red[5]) + (red[6] + red[7]));
  #pragma unroll
  for (int i = 0; i < 4; ++i) {
    int n = i * 256 + tid;
    if (n < NCLS) out[(size_t)b * NCLS + n] = e[i] * inv;
  }
}

// ---------------- launch ----------------
extern "C" void kernel_launch(void* const* d_in, const int* in_sizes, int n_in,
                              void* d_out, int out_size, void* d_ws, size_t ws_size,
                              hipStream_t stream) {
  const float* x        = (const float*)d_in[0];
  const float* class_tk = (const float*)d_in[1];
  const float* pos_emb  = (const float*)d_in[2];
  const float* patch_w  = (const float*)d_in[3];
  const float* patch_b  = (const float*)d_in[4];
  const float* wq       = (const float*)d_in[5];
  const float* wk       = (const float*)d_in[6];
  const float* wv       = (const float*)d_in[7];
  const float* proj_w   = (const float*)d_in[8];
  const float* proj_b   = (const float*)d_in[9];
  const float* mlp_w1   = (const float*)d_in[10];
  const float* mlp_b1   = (const float*)d_in[11];
  const float* mlp_w2   = (const float*)d_in[12];
  const float* mlp_b2   = (const float*)d_in[13];
  const float* ln1_g    = (const float*)d_in[14];
  const float* ln1_b    = (const float*)d_in[15];
  const float* ln2_g    = (const float*)d_in[16];
  const float* ln2_b    = (const float*)d_in[17];
  const float* head_w   = (const float*)d_in[18];
  const float* head_b   = (const float*)d_in[19];
  float* out = (float*)d_out;

  float* ws = (float*)d_ws;
  const size_t NTOK = (size_t)M_ROWS * D;   // 526336
  float* t     = ws;                            // [2056][256] fp32
  u16*  xnh    = (u16*)(ws + NTOK);             // ln1 split planes
  u16*  xnl    = xnh + NTOK;
  float* kk    = ws + 2 * NTOK;                 // K transposed [b][h][s]
  float* v     = ws + 3 * NTOK;                 // V transposed
  float* ocls  = ws + 4 * NTOK;                 // [8][256]
  u16*  Wkv    = (u16*)(ws + 4 * NTOK + 4096);  // kh,kl,vh,vl (4*65536 u16)
  float* TAIL  = ws + 5 * NTOK;
  float* tnbuf = TAIL;                 // [8][256]
  float* xn2   = TAIL + 2048;          // [8][256]
  float* pA    = TAIL + 4096;          // [8][8][256]   = 16384
  float* pB    = pA + 16384;           // [8][8][1024]  = 65536
  float* pC    = pB + 65536;           // [32][8][256]  = 65536
  float* pD    = pC + 65536;           // [16][8][1024] = 131072

  stage0<<<1359, 256, 0, stream>>>(x, patch_w, patch_b, pos_emb, class_tk,
                                   wk, wv, proj_w, mlp_w1, mlp_w2, head_w, Wkv, t);

  ln_split<<<(M_ROWS + 3) / 4, 256, 0, stream>>>(t, xnh, xnl, ln1_g, ln1_b, M_ROWS);

  kv_kernel<<<dim3(4, 33, 2), 256, 0, stream>>>(xnh, xnl, Wkv, kk, v);

  attn_cls<<<dim3(256, Bsz), 256, 0, stream>>>(xnh, xnl, wq, kk, v, ocls);

  proj_part<<<64, 256, 0, stream>>>(ocls, proj_w, pA);
  proj_red_ln<<<Bsz, 256, 0, stream>>>(pA, proj_b, t, ln2_g, ln2_b, tnbuf, xn2);

  mlp1_part<<<32, 256, 0, stream>>>(xn2, mlp_w1, pB);

  mlp2_part<<<32, 256, 0, stream>>>(pB, mlp_b1, mlp_w2, pC);

  head_part<<<64, 256, 0, stream>>>(pC, mlp_b2, tnbuf, head_w, pD);

  softmax_kernel<<<Bsz, 256, 0, stream>>>(pD, head_b, out);
}